// Round 2
// baseline (6281.197 us; speedup 1.0000x reference)
//
#include <hip/hip_runtime.h>
#include <hip/hip_bf16.h>

typedef __hip_bfloat16 bf16;

#define NP    2048
#define DC    256
#define HA_   1024
#define HP_   64
#define MA    128
#define KNN_  16

__device__ __forceinline__ float u2f(unsigned short u){ return __uint_as_float(((unsigned int)u)<<16); }
__device__ __forceinline__ unsigned short f2u(float f){ bf16 h=__float2bfloat16(f); unsigned short us; __builtin_memcpy(&us,&h,2); return us; }

// ---------------- generic small GEMM: out = W(MxK) @ X + bias (+resid) ----------------
// X: (b,K,N) if !XT, (b,N,K) if XT.  out: (b,M,N) if !OT, (b,N,M) if OT.
template<bool XT, bool OT, bool RES>
__global__ __launch_bounds__(256) void gemm_k(
    const float* __restrict__ W, const float* __restrict__ X,
    const float* __restrict__ bias, const float* __restrict__ resid,
    float* __restrict__ out, int M, int N, int K)
{
  __shared__ float Ws[16][65];
  __shared__ float Xs[16][65];
  const int tid = threadIdx.x;
  const int tx = tid & 15, ty = tid >> 4;
  const int n0 = blockIdx.x * 64, m0 = blockIdx.y * 64, bb = blockIdx.z;
  float c[4][4] = {};
  for (int k0 = 0; k0 < K; k0 += 16) {
#pragma unroll
    for (int ldi = 0; ldi < 4; ldi++) {
      int e = tid + ldi * 256;
      int m = e >> 4, kk = e & 15;
      Ws[kk][m] = W[(size_t)(m0 + m) * K + k0 + kk];
    }
#pragma unroll
    for (int ldi = 0; ldi < 4; ldi++) {
      int e = tid + ldi * 256;
      if constexpr (!XT) {
        int kk = e >> 6, nn = e & 63;
        Xs[kk][nn] = X[(size_t)bb * K * N + (size_t)(k0 + kk) * N + n0 + nn];
      } else {
        int nn = e >> 4, kk = e & 15;
        Xs[kk][nn] = X[(size_t)bb * N * K + (size_t)(n0 + nn) * K + k0 + kk];
      }
    }
    __syncthreads();
#pragma unroll
    for (int kk = 0; kk < 16; kk++) {
      float av[4], bv[4];
#pragma unroll
      for (int q = 0; q < 4; q++) { av[q] = Ws[kk][ty*4+q]; bv[q] = Xs[kk][tx*4+q]; }
#pragma unroll
      for (int q = 0; q < 4; q++)
#pragma unroll
        for (int r = 0; r < 4; r++) c[q][r] += av[q] * bv[r];
    }
    __syncthreads();
  }
#pragma unroll
  for (int q = 0; q < 4; q++) {
    int m = m0 + ty*4 + q;
    float bsv = bias[m];
#pragma unroll
    for (int r = 0; r < 4; r++) {
      int n = n0 + tx*4 + r;
      float v = c[q][r] + bsv;
      if constexpr (RES) v += resid[(size_t)bb * M * N + (size_t)m * N + n];
      if constexpr (!OT) out[(size_t)bb * M * N + (size_t)m * N + n] = v;
      else               out[(size_t)bb * N * M + (size_t)n * M + m] = v;
    }
  }
}

// ---------------- KNN top-16 (matches top_k(-d) tie semantics: lower index wins) -------
__global__ __launch_bounds__(64) void knn_kernel(const float* __restrict__ pos, int* __restrict__ idx)
{
  __shared__ float px[NP], py[NP], pz[NP], pn[NP];
  const int tid = threadIdx.x;
  const int bb = blockIdx.x >> 5;          // 32 blocks per batch
  const int i0 = (blockIdx.x & 31) * 64;
  const float* pp = pos + (size_t)bb * 3 * NP;
  for (int t = tid; t < NP; t += 64) {
    float x = pp[t], y = pp[NP + t], z = pp[2*NP + t];
    px[t] = x; py[t] = y; pz[t] = z; pn[t] = x*x + y*y + z*z;
  }
  __syncthreads();
  const int qi = i0 + tid;
  const float qx = px[qi], qy = py[qi], qz = pz[qi], qn = pn[qi];
  float bd[KNN_]; int bi[KNN_];
#pragma unroll
  for (int t = 0; t < KNN_; t++) { bd[t] = 3.4e38f; bi[t] = 0; }
  float worst = 3.4e38f;
  for (int j = 0; j < NP; j++) {
    float d = qn + pn[j] - 2.f * (qx*px[j] + qy*py[j] + qz*pz[j]);
    if (d < worst) {
      int p = KNN_ - 1;
      while (p > 0 && d < bd[p-1]) { bd[p] = bd[p-1]; bi[p] = bi[p-1]; p--; }
      bd[p] = d; bi[p] = j;
      worst = bd[KNN_-1];
    }
  }
  int* op_ = idx + ((size_t)bb * NP + qi) * KNN_;
#pragma unroll
  for (int t = 0; t < KNN_; t++) op_[t] = bi[t];
}

// ---------------- weight prep: transposes + BN folding (all f32) ----------------
__global__ __launch_bounds__(256) void prep_kernel(
    const float* __restrict__ aw2, const float* __restrict__ lw3, const float* __restrict__ pw2,
    const float* __restrict__ ag1, const float* __restrict__ ab1, const float* __restrict__ abt1,
    const float* __restrict__ pg1, const float* __restrict__ pb1, const float* __restrict__ pbt1,
    float* __restrict__ aw2Tf, float* __restrict__ lw3Tf, float* __restrict__ pw2Tf,
    float* __restrict__ sa, float* __restrict__ oa, float* __restrict__ sp, float* __restrict__ op_)
{
  int i = blockIdx.x * blockDim.x + threadIdx.x;
  const float inv = rsqrtf(1.0f + 1e-5f);
  if (i < 262144) { int h = i >> 8, c = i & 255; aw2Tf[i] = aw2[(size_t)c*1024 + h]; return; }
  i -= 262144;
  if (i < 16384) { int h = i >> 8, c = i & 255; lw3Tf[i] = lw3[c*64 + h]; return; }
  i -= 16384;
  if (i < 16384) { int h = i >> 8, c = i & 255; pw2Tf[i] = pw2[c*64 + h]; return; }
  i -= 16384;
  if (i < 1024){ float s_ = ag1[i] * inv; sa[i] = s_; oa[i] = ab1[i]*s_ + abt1[i]; return; }
  i -= 1024;
  if (i < 64)  { float s_ = pg1[i] * inv; sp[i] = s_; op_[i] = pb1[i]*s_ + pbt1[i]; return; }
}

#define FMA4(ACC, T4, WV, HV) \
  ACC[(T4)*4+0] += (WV).x*(HV); ACC[(T4)*4+1] += (WV).y*(HV); \
  ACC[(T4)*4+2] += (WV).z*(HV); ACC[(T4)*4+3] += (WV).w*(HV);

// ---------------- fused geometric MLPs + attention MLP + softmax + aggregation --------
// 1 wave per point, 4 points per block.
__global__ __launch_bounds__(256, 2) void fused_attn(
    const float* __restrict__ keyT, const float* __restrict__ queryT,
    const float* __restrict__ valueT, const int* __restrict__ knn_idx,
    const float* __restrict__ pos, const int* __restrict__ map_idx,
    const float* __restrict__ P_anchor, const float* __restrict__ adist,
    const float* __restrict__ lw1f, const float* __restrict__ lw2f, const float* __restrict__ lw3Tf,
    const float* __restrict__ pw1f, const float* __restrict__ spv, const float* __restrict__ opv,
    const float* __restrict__ pw2Tf, const float* __restrict__ pb2f,
    const float* __restrict__ aw1f, const float* __restrict__ sav, const float* __restrict__ oav,
    const float* __restrict__ aw2Tf, const float* __restrict__ ab2f,
    float* __restrict__ aggT)
{
  __shared__ unsigned short s_s [4][DC ][17];   // s = qk_rel + pos_emb + f_l (bf16)
  __shared__ unsigned short s_h1[4][32 ][17];
  __shared__ unsigned short s_h2[4][HP_][17];   // h2, later reused for ph
  __shared__ unsigned short s_hid[4][HP_][17];
  __shared__ float s_feat[4][6][17];
  __shared__ float s_prel[4][3][17];
  __shared__ int   s_idx[4][16];

  const int tid = threadIdx.x;
  const int w = tid >> 6, l = tid & 63;
  const int k = l & 15, g = l >> 4;
  const int cg = g * 64;
  const int p = blockIdx.x * 4 + w;
  const int b = p >> 11, pi = p & 2047;

  // ---- P0: geometric features (16 lanes) ----
  if (l < 16) {
    int kk = l;
    int j = knn_idx[((size_t)(b*NP) + pi) * KNN_ + kk];
    s_idx[w][kk] = j;
    const float* pp = pos + (size_t)b * 3 * NP;
    float qx = pp[pi], qy = pp[NP+pi], qz = pp[2*NP+pi];
    float nx = pp[j],  ny = pp[NP+j],  nz = pp[2*NP+j];
    float r1x = qx-nx, r1y = qy-ny, r1z = qz-nz;
    s_prel[w][0][kk] = r1x; s_prel[w][1][kk] = r1y; s_prel[w][2][kk] = r1z;
    int mi = map_idx[b*NP + pi];
    int bj = map_idx[b*NP + j];
    const float* pa = P_anchor + (size_t)b * MA * 3;
    float ax = pa[mi*3], ay = pa[mi*3+1], az = pa[mi*3+2];
    float bx = pa[bj*3], by = pa[bj*3+1], bz = pa[bj*3+2];
    float dA = sqrtf((qx-ax)*(qx-ax)+(qy-ay)*(qy-ay)+(qz-az)*(qz-az));
    float dB = sqrtf((nx-bx)*(nx-bx)+(ny-by)*(ny-by)+(nz-bz)*(nz-bz));
    float dAB = adist[(size_t)b*MA*MA + mi*MA + bj];
    float r2 = dA + dAB + dB;
    s_feat[w][0][kk] = fabsf(r1x); s_feat[w][1][kk] = fabsf(r1y); s_feat[w][2][kk] = fabsf(r1z);
    s_feat[w][3][kk] = r2; s_feat[w][4][kk] = r2; s_feat[w][5][kk] = r2;
  }
  __syncthreads();

  // ---- P1: h1 = relu(lw1 @ feats)  (32 x 16) ----
  {
    float f0=s_feat[w][0][k], f1=s_feat[w][1][k], f2=s_feat[w][2][k],
          f3=s_feat[w][3][k], f4=s_feat[w][4][k], f5=s_feat[w][5][k];
#pragma unroll
    for (int jj = 0; jj < 8; jj++) {
      int h = g*8 + jj;
      const float* wp = lw1f + h*6;
      float v = wp[0]*f0 + wp[1]*f1 + wp[2]*f2 + wp[3]*f3 + wp[4]*f4 + wp[5]*f5;
      s_h1[w][h][k] = f2u(fmaxf(v, 0.f));
    }
  }
  __syncthreads();

  // ---- P2: h2 = relu(lw2 @ h1)  (64 x 16) ----
  {
    float hr[32];
#pragma unroll
    for (int t = 0; t < 32; t++) hr[t] = u2f(s_h1[w][t][k]);
#pragma unroll
    for (int jj = 0; jj < 16; jj++) {
      int h = g*16 + jj;
      const float4* wp = (const float4*)(lw2f + h*32);
      float a = 0.f;
#pragma unroll
      for (int t4 = 0; t4 < 8; t4++) {
        float4 wv = wp[t4];
        a += wv.x*hr[t4*4] + wv.y*hr[t4*4+1] + wv.z*hr[t4*4+2] + wv.w*hr[t4*4+3];
      }
      s_h2[w][h][k] = f2u(fmaxf(a, 0.f));
    }
  }
  __syncthreads();

  float acc[64];
  // ---- P3a: acc = query - key_g, += f_l = lw3T @ h2 ----
  {
    int jk = s_idx[w][k];
    const float4* qp = (const float4*)(queryT + ((size_t)(b*NP) + pi)*DC + cg);
    const float4* kp = (const float4*)(keyT  + ((size_t)(b*NP) + jk)*DC + cg);
#pragma unroll
    for (int t4 = 0; t4 < 16; t4++) {
      float4 q4 = qp[t4], k4 = kp[t4];
      acc[t4*4+0] = q4.x-k4.x; acc[t4*4+1] = q4.y-k4.y;
      acc[t4*4+2] = q4.z-k4.z; acc[t4*4+3] = q4.w-k4.w;
    }
#pragma unroll 2
    for (int h = 0; h < HP_; h++) {
      float hv = u2f(s_h2[w][h][k]);
      const float4* wp = (const float4*)(lw3Tf + h*DC + cg);
#pragma unroll
      for (int t4 = 0; t4 < 16; t4++) { float4 wv = wp[t4]; FMA4(acc, t4, wv, hv); }
    }
  }
  __syncthreads();   // h2 consumed; reuse s_h2 for ph

  // ---- P2.5: ph = relu(bn(pw1 @ pos_rel)) into s_h2 ----
  {
    float p0 = s_prel[w][0][k], p1 = s_prel[w][1][k], p2 = s_prel[w][2][k];
#pragma unroll
    for (int jj = 0; jj < 16; jj++) {
      int h = g*16 + jj;
      float d = pw1f[h*3]*p0 + pw1f[h*3+1]*p1 + pw1f[h*3+2]*p2;
      float v = d*spv[h] + opv[h];
      s_h2[w][h][k] = f2u(fmaxf(v, 0.f));
    }
  }
  __syncthreads();

  // ---- P3b: acc += pos_emb = pw2T @ ph + pb2 ; store s ----
  {
#pragma unroll 2
    for (int h = 0; h < HP_; h++) {
      float hv = u2f(s_h2[w][h][k]);
      const float4* wp = (const float4*)(pw2Tf + h*DC + cg);
#pragma unroll
      for (int t4 = 0; t4 < 16; t4++) { float4 wv = wp[t4]; FMA4(acc, t4, wv, hv); }
    }
    const float4* bp = (const float4*)(pb2f + cg);
#pragma unroll
    for (int t4 = 0; t4 < 16; t4++) {
      float4 bv = bp[t4];
      acc[t4*4+0] += bv.x; acc[t4*4+1] += bv.y; acc[t4*4+2] += bv.z; acc[t4*4+3] += bv.w;
      s_s[w][cg+t4*4+0][k] = f2u(acc[t4*4+0]);
      s_s[w][cg+t4*4+1][k] = f2u(acc[t4*4+1]);
      s_s[w][cg+t4*4+2][k] = f2u(acc[t4*4+2]);
      s_s[w][cg+t4*4+3][k] = f2u(acc[t4*4+3]);
    }
  }
  __syncthreads();

  // ---- a2 init with ab2 ----
  {
    const float4* bp = (const float4*)(ab2f + cg);
#pragma unroll
    for (int t4 = 0; t4 < 16; t4++) {
      float4 bv = bp[t4];
      acc[t4*4+0] = bv.x; acc[t4*4+1] = bv.y; acc[t4*4+2] = bv.z; acc[t4*4+3] = bv.w;
    }
  }

  // ---- P5: 16 chunks of 64 hidden channels: hid = relu(bn(aw1@s)), a2 += aw2T@hid ----
  for (int hc = 0; hc < 16; hc++) {
    float aj[16];
#pragma unroll
    for (int jj = 0; jj < 16; jj++) aj[jj] = 0.f;
    for (int cb = 0; cb < 8; cb++) {
      float sr[32];
#pragma unroll
      for (int t = 0; t < 32; t++) sr[t] = u2f(s_s[w][cb*32+t][k]);
#pragma unroll
      for (int jj = 0; jj < 16; jj++) {
        const float4* wp = (const float4*)(aw1f + ((size_t)(hc*64 + g*16 + jj))*DC + cb*32);
#pragma unroll
        for (int t4 = 0; t4 < 8; t4++) {
          float4 wv = wp[t4];
          aj[jj] += wv.x*sr[t4*4] + wv.y*sr[t4*4+1] + wv.z*sr[t4*4+2] + wv.w*sr[t4*4+3];
        }
      }
    }
#pragma unroll
    for (int jj = 0; jj < 16; jj++) {
      int h = hc*64 + g*16 + jj;
      float v = aj[jj]*sav[h] + oav[h];
      s_hid[w][g*16+jj][k] = f2u(fmaxf(v, 0.f));
    }
    __syncthreads();
#pragma unroll 2
    for (int hl = 0; hl < 64; hl++) {
      float hv = u2f(s_hid[w][hl][k]);
      const float4* wp = (const float4*)(aw2Tf + ((size_t)(hc*64 + hl))*DC + cg);
#pragma unroll
      for (int t4 = 0; t4 < 16; t4++) { float4 wv = wp[t4]; FMA4(acc, t4, wv, hv); }
    }
    __syncthreads();
  }

  // ---- P6: softmax over k (width-16 shuffles) + aggregation + store aggT ----
  {
    int jk = s_idx[w][k];
    const float4* qp = (const float4*)(queryT + ((size_t)(b*NP) + pi)*DC + cg);
    const float4* kp = (const float4*)(keyT  + ((size_t)(b*NP) + jk)*DC + cg);
    const float4* vp = (const float4*)(valueT + ((size_t)(b*NP) + pi)*DC + cg);
    float* aggp = aggT + ((size_t)(b*NP) + pi)*DC + cg;
#pragma unroll
    for (int t4 = 0; t4 < 16; t4++) {
      float4 q4 = qp[t4], k4 = kp[t4], v4 = vp[t4];
      float res[4];
#pragma unroll
      for (int e = 0; e < 4; e++) {
        int t = t4*4 + e;
        float a = acc[t];
        float m = a;
        m = fmaxf(m, __shfl_xor(m, 1, 16)); m = fmaxf(m, __shfl_xor(m, 2, 16));
        m = fmaxf(m, __shfl_xor(m, 4, 16)); m = fmaxf(m, __shfl_xor(m, 8, 16));
        float ex = __expf(a - m);
        float se = ex;
        se += __shfl_xor(se, 1, 16); se += __shfl_xor(se, 2, 16);
        se += __shfl_xor(se, 4, 16); se += __shfl_xor(se, 8, 16);
        float watt = ex / se;
        float sv = u2f(s_s[w][cg+t][k]);
        float qe = (e==0) ? q4.x : (e==1) ? q4.y : (e==2) ? q4.z : q4.w;
        float ke = (e==0) ? k4.x : (e==1) ? k4.y : (e==2) ? k4.z : k4.w;
        float ve = (e==0) ? v4.x : (e==1) ? v4.y : (e==2) ? v4.z : v4.w;
        float vev = ve - qe + sv + ke;          // value + (pos_emb+f_l)
        float cc = watt * vev;
        cc += __shfl_xor(cc, 1, 16); cc += __shfl_xor(cc, 2, 16);
        cc += __shfl_xor(cc, 4, 16); cc += __shfl_xor(cc, 8, 16);
        res[e] = cc;
      }
      if (k == 0) ((float4*)aggp)[t4] = make_float4(res[0], res[1], res[2], res[3]);
    }
  }
}

// ---------------- launch ----------------
extern "C" void kernel_launch(void* const* d_in, const int* in_sizes, int n_in,
                              void* d_out, int out_size, void* d_ws, size_t ws_size,
                              hipStream_t stream)
{
  const float* x        = (const float*)d_in[0];
  const float* pos      = (const float*)d_in[1];
  const float* P_anchor = (const float*)d_in[3];
  const int*   map_idx  = (const int*)  d_in[4];
  const float* adist    = (const float*)d_in[5];
  const float* w_start  = (const float*)d_in[6];
  const float* b_start  = (const float*)d_in[7];
  const float* w_key    = (const float*)d_in[8];
  const float* b_key    = (const float*)d_in[9];
  const float* w_query  = (const float*)d_in[10];
  const float* b_query  = (const float*)d_in[11];
  const float* w_value  = (const float*)d_in[12];
  const float* b_value  = (const float*)d_in[13];
  const float* pw1      = (const float*)d_in[14];
  const float* pg1      = (const float*)d_in[16];
  const float* pb1      = (const float*)d_in[15];
  const float* pbt1     = (const float*)d_in[17];
  const float* pw2      = (const float*)d_in[18];
  const float* pb2      = (const float*)d_in[19];
  const float* lw1      = (const float*)d_in[20];
  const float* lw2      = (const float*)d_in[21];
  const float* lw3      = (const float*)d_in[22];
  const float* aw1      = (const float*)d_in[23];
  const float* ab1      = (const float*)d_in[24];
  const float* ag1      = (const float*)d_in[25];
  const float* abt1     = (const float*)d_in[26];
  const float* aw2      = (const float*)d_in[27];
  const float* ab2      = (const float*)d_in[28];
  const float* w_end    = (const float*)d_in[29];
  const float* b_end    = (const float*)d_in[30];

  if (ws_size < (size_t)5605504 * 4) return;   // clean wrong-answer instead of corruption

  float* ws     = (float*)d_ws;
  float* xf     = ws + 0;
  float* keyT   = ws + 1048576;
  float* queryT = ws + 2097152;
  float* valueT = ws + 3145728;
  float* aggT   = ws + 4194304;
  float* aw2Tf  = ws + 5242880;
  float* lw3Tf  = ws + 5505024;
  float* pw2Tf  = ws + 5521408;
  float* sa     = ws + 5537792;
  float* oa     = ws + 5538816;
  float* sp     = ws + 5539840;
  float* op_    = ws + 5539904;
  int*   knn_i  = (int*)(ws + 5539968);
  // end: 5539968 + 65536 = 5605504 floats

  prep_kernel<<<1157, 256, 0, stream>>>(aw2, lw3, pw2,
      ag1, ab1, abt1, pg1, pb1, pbt1,
      aw2Tf, lw3Tf, pw2Tf, sa, oa, sp, op_);

  gemm_k<false, false, false><<<dim3(32,4,2), 256, 0, stream>>>(
      w_start, x, b_start, nullptr, xf, 256, NP, 128);

  knn_kernel<<<64, 64, 0, stream>>>(pos, knn_i);

  gemm_k<false, true, false><<<dim3(32,4,2), 256, 0, stream>>>(
      w_key,   xf, b_key,   nullptr, keyT,   256, NP, 256);
  gemm_k<false, true, false><<<dim3(32,4,2), 256, 0, stream>>>(
      w_query, xf, b_query, nullptr, queryT, 256, NP, 256);
  gemm_k<false, true, false><<<dim3(32,4,2), 256, 0, stream>>>(
      w_value, xf, b_value, nullptr, valueT, 256, NP, 256);

  fused_attn<<<1024, 256, 0, stream>>>(keyT, queryT, valueT, knn_i,
      pos, map_idx, P_anchor, adist,
      lw1, lw2, lw3Tf, pw1, sp, op_, pw2Tf, pb2,
      aw1, sa, oa, aw2Tf, ab2, aggT);

  gemm_k<true, false, true><<<dim3(32,2,2), 256, 0, stream>>>(
      w_end, aggT, b_end, x, (float*)d_out, 128, NP, 256);
}

// Round 3
// 1125.983 us; speedup vs baseline: 5.5784x; 5.5784x over previous
//
#include <hip/hip_runtime.h>
#include <hip/hip_bf16.h>

typedef __hip_bfloat16 bf16;
typedef unsigned short u16;
typedef __attribute__((ext_vector_type(8))) short s8v;    // 8 bf16 (4 VGPRs) MFMA frag
typedef __attribute__((ext_vector_type(4))) float f32x4;  // MFMA acc frag

#define NP    2048
#define DC    256
#define MA    128
#define KNN_  16

#define MFMA_B16(a,b,c) __builtin_amdgcn_mfma_f32_16x16x32_bf16(a,b,c,0,0,0)

__device__ __forceinline__ float u2f(u16 u){ return __uint_as_float(((unsigned int)u)<<16); }
__device__ __forceinline__ u16 f2u(float f){ bf16 h=__float2bfloat16(f); u16 us; __builtin_memcpy(&us,&h,2); return us; }

// packed A-frag load: layout [((rb*KS+ks)*64+l)*8 + j]
__device__ __forceinline__ s8v ldpk(const u16* pk, int rb, int KS, int ks, int l){
  return *(const s8v*)(pk + (((size_t)((rb*KS + ks)*64 + l))<<3));
}
// LDS B-frag read, 16B, XOR-swizzled. rshift = log2(row bytes)
__device__ __forceinline__ s8v ldsB(const u16* base, int col, int k0, int rshift){
  int byte = ((col<<rshift) + (k0<<1)) ^ ((col&7)<<4);
  return *(const s8v*)((const char*)base + byte);
}
// LDS 4x bf16 write (8B), swizzled
__device__ __forceinline__ void st2(u16* base, int col, int ch0, int rshift,
                                    float v0, float v1, float v2, float v3){
  uint2 pkv;
  pkv.x = (unsigned)f2u(v0) | ((unsigned)f2u(v1)<<16);
  pkv.y = (unsigned)f2u(v2) | ((unsigned)f2u(v3)<<16);
  int byte = ((col<<rshift) + (ch0<<1)) ^ ((col&7)<<4);
  *(uint2*)((char*)base + byte) = pkv;
}
// LDS single bf16 write, swizzled
__device__ __forceinline__ void st1(u16* base, int col, int ch, int rshift, float v){
  int byte = ((col<<rshift) + (ch<<1)) ^ ((col&7)<<4);
  *(u16*)((char*)base + byte) = f2u(v);
}
// LDS 4x bf16 read (8B), swizzled
__device__ __forceinline__ void ld4s(const u16* base, int col, int ch0, int rshift, float* o){
  int byte = ((col<<rshift) + (ch0<<1)) ^ ((col&7)<<4);
  uint2 pkv = *(const uint2*)((const char*)base + byte);
  o[0] = u2f(pkv.x & 0xffff); o[1] = u2f(pkv.x>>16);
  o[2] = u2f(pkv.y & 0xffff); o[3] = u2f(pkv.y>>16);
}

// ---------------- generic small GEMM (f32 vector path, unchanged) ----------------
template<bool XT, bool OT, bool RES>
__global__ __launch_bounds__(256) void gemm_k(
    const float* __restrict__ W, const float* __restrict__ X,
    const float* __restrict__ bias, const float* __restrict__ resid,
    float* __restrict__ out, int M, int N, int K)
{
  __shared__ float Ws[16][65];
  __shared__ float Xs[16][65];
  const int tid = threadIdx.x;
  const int tx = tid & 15, ty = tid >> 4;
  const int n0 = blockIdx.x * 64, m0 = blockIdx.y * 64, bb = blockIdx.z;
  float c[4][4] = {};
  for (int k0 = 0; k0 < K; k0 += 16) {
#pragma unroll
    for (int ldi = 0; ldi < 4; ldi++) {
      int e = tid + ldi * 256;
      int m = e >> 4, kk = e & 15;
      Ws[kk][m] = W[(size_t)(m0 + m) * K + k0 + kk];
    }
#pragma unroll
    for (int ldi = 0; ldi < 4; ldi++) {
      int e = tid + ldi * 256;
      if constexpr (!XT) {
        int kk = e >> 6, nn = e & 63;
        Xs[kk][nn] = X[(size_t)bb * K * N + (size_t)(k0 + kk) * N + n0 + nn];
      } else {
        int nn = e >> 4, kk = e & 15;
        Xs[kk][nn] = X[(size_t)bb * N * K + (size_t)(n0 + nn) * K + k0 + kk];
      }
    }
    __syncthreads();
#pragma unroll
    for (int kk = 0; kk < 16; kk++) {
      float av[4], bv[4];
#pragma unroll
      for (int q = 0; q < 4; q++) { av[q] = Ws[kk][ty*4+q]; bv[q] = Xs[kk][tx*4+q]; }
#pragma unroll
      for (int q = 0; q < 4; q++)
#pragma unroll
        for (int r = 0; r < 4; r++) c[q][r] += av[q] * bv[r];
    }
    __syncthreads();
  }
#pragma unroll
  for (int q = 0; q < 4; q++) {
    int m = m0 + ty*4 + q;
    float bsv = bias[m];
#pragma unroll
    for (int r = 0; r < 4; r++) {
      int n = n0 + tx*4 + r;
      float v = c[q][r] + bsv;
      if constexpr (RES) v += resid[(size_t)bb * M * N + (size_t)m * N + n];
      if constexpr (!OT) out[(size_t)bb * M * N + (size_t)m * N + n] = v;
      else               out[(size_t)bb * N * M + (size_t)n * M + m] = v;
    }
  }
}

// ---------------- KNN top-16 ----------------
__global__ __launch_bounds__(64) void knn_kernel(const float* __restrict__ pos, int* __restrict__ idx)
{
  __shared__ float px[NP], py[NP], pz[NP], pn[NP];
  const int tid = threadIdx.x;
  const int bb = blockIdx.x >> 5;
  const int i0 = (blockIdx.x & 31) * 64;
  const float* pp = pos + (size_t)bb * 3 * NP;
  for (int t = tid; t < NP; t += 64) {
    float x = pp[t], y = pp[NP + t], z = pp[2*NP + t];
    px[t] = x; py[t] = y; pz[t] = z; pn[t] = x*x + y*y + z*z;
  }
  __syncthreads();
  const int qi = i0 + tid;
  const float qx = px[qi], qy = py[qi], qz = pz[qi], qn = pn[qi];
  float bd[KNN_]; int bi[KNN_];
#pragma unroll
  for (int t = 0; t < KNN_; t++) { bd[t] = 3.4e38f; bi[t] = 0; }
  float worst = 3.4e38f;
  for (int j = 0; j < NP; j++) {
    float d = qn + pn[j] - 2.f * (qx*px[j] + qy*py[j] + qz*pz[j]);
    if (d < worst) {
      int p = KNN_ - 1;
      while (p > 0 && d < bd[p-1]) { bd[p] = bd[p-1]; bi[p] = bi[p-1]; p--; }
      bd[p] = d; bi[p] = j;
      worst = bd[KNN_-1];
    }
  }
  int* op_ = idx + ((size_t)bb * NP + qi) * KNN_;
#pragma unroll
  for (int t = 0; t < KNN_; t++) op_[t] = bi[t];
}

// ---------------- prep: pack MFMA A-fragments (bf16) + BN folds ----------------
__global__ __launch_bounds__(256) void prep_kernel(
    const float* __restrict__ aw1, const float* __restrict__ aw2,
    const float* __restrict__ lw3, const float* __restrict__ pw2,
    const float* __restrict__ ag1, const float* __restrict__ ab1, const float* __restrict__ abt1,
    const float* __restrict__ pg1, const float* __restrict__ pb1, const float* __restrict__ pbt1,
    u16* __restrict__ aw1pk, u16* __restrict__ aw2pk, u16* __restrict__ wppk,
    float* __restrict__ sa, float* __restrict__ oa, float* __restrict__ sp, float* __restrict__ op_)
{
  int i = blockIdx.x * 256 + threadIdx.x;
  const float inv = rsqrtf(1.0f + 1e-5f);
  if (i < 262144) {  // aw1 (1024x256), KS=8, rb-stride 4096
    int rb = i >> 12, rem = i & 4095, ks = rem >> 9, l = (rem >> 3) & 63, j = rem & 7;
    int row = rb*16 + (l & 15), colk = ks*32 + (l >> 4)*8 + j;
    aw1pk[i] = f2u(aw1[(size_t)row*256 + colk]); return;
  }
  i -= 262144;
  if (i < 262144) {  // aw2 (256x1024), KS=32, rb-stride 16384
    int rb = i >> 14, rem = i & 16383, ks = rem >> 9, l = (rem >> 3) & 63, j = rem & 7;
    int row = rb*16 + (l & 15), colk = ks*32 + (l >> 4)*8 + j;
    aw2pk[i] = f2u(aw2[(size_t)row*1024 + colk]); return;
  }
  i -= 262144;
  if (i < 32768) {   // W' = [lw3 | pw2] (256x128), KS=4, rb-stride 2048
    int rb = i >> 11, rem = i & 2047, ks = rem >> 9, l = (rem >> 3) & 63, j = rem & 7;
    int row = rb*16 + (l & 15), colk = ks*32 + (l >> 4)*8 + j;
    float v = (colk < 64) ? lw3[row*64 + colk] : pw2[row*64 + (colk - 64)];
    wppk[i] = f2u(v); return;
  }
  i -= 32768;
  if (i < 1024) { float s_ = ag1[i]*inv; sa[i] = s_; oa[i] = ab1[i]*s_ + abt1[i]; return; }
  i -= 1024;
  if (i < 64)  { float s_ = pg1[i]*inv; sp[i] = s_; op_[i] = pb1[i]*s_ + pbt1[i]; return; }
}

// ---------------- fused: geometric MLPs + MFMA attention MLP + softmax + agg ----------
// block = 4 waves = 4 points = 64 (point,k) columns
__global__ __launch_bounds__(256, 2) void fused_attn(
    const float* __restrict__ keyT, const float* __restrict__ queryT,
    const float* __restrict__ valueT, const int* __restrict__ knn_idx,
    const float* __restrict__ pos, const int* __restrict__ map_idx,
    const float* __restrict__ P_anchor, const float* __restrict__ adist,
    const float* __restrict__ lw1f, const float* __restrict__ lw2f, const float* __restrict__ pw1f,
    const float* __restrict__ spv, const float* __restrict__ opv, const float* __restrict__ pb2f,
    const u16* __restrict__ aw1pk, const float* __restrict__ sav, const float* __restrict__ oav,
    const u16* __restrict__ aw2pk, const u16* __restrict__ wppk, const float* __restrict__ ab2f,
    float* __restrict__ aggT)
{
  __shared__ u16 s_t[64*256];     // s tile [col][ch], bf16, XOR-swizzled (row=512B)
  __shared__ u16 hid_t[64*128];   // H (geom hidden) then hid chunks [col][kk] (row=256B)
  __shared__ u16 s_h1[4][32][17];
  __shared__ float s_feat[4][6][17];
  __shared__ float s_prel[4][3][17];
  __shared__ int   s_idx[4][16];

  const int tid = threadIdx.x;
  const int w = tid >> 6, l = tid & 63;
  const int k = l & 15, g = l >> 4;
  const int p0 = blockIdx.x * 4;
  const int b = p0 >> 11, pi0 = p0 & 2047;
  const int pi = pi0 + w;            // phase-1: wave w owns point pi
  const int col_w = w*16 + k;        // phase-1 column

  const float* qB = queryT + ((size_t)b * NP) * DC;
  const float* kB = keyT   + ((size_t)b * NP) * DC;
  const float* vB = valueT + ((size_t)b * NP) * DC;

  // ---- P0: geometric features (16 lanes per wave) ----
  if (l < 16) {
    int kk = l;
    int j = knn_idx[((size_t)(b*NP) + pi) * KNN_ + kk];
    s_idx[w][kk] = j;
    const float* pp = pos + (size_t)b * 3 * NP;
    float qx = pp[pi], qy = pp[NP+pi], qz = pp[2*NP+pi];
    float nx = pp[j],  ny = pp[NP+j],  nz = pp[2*NP+j];
    float r1x = qx-nx, r1y = qy-ny, r1z = qz-nz;
    s_prel[w][0][kk] = r1x; s_prel[w][1][kk] = r1y; s_prel[w][2][kk] = r1z;
    int mi = map_idx[b*NP + pi];
    int bj = map_idx[b*NP + j];
    const float* pa = P_anchor + (size_t)b * MA * 3;
    float ax = pa[mi*3], ay = pa[mi*3+1], az = pa[mi*3+2];
    float bx = pa[bj*3], by = pa[bj*3+1], bz = pa[bj*3+2];
    float dA = sqrtf((qx-ax)*(qx-ax)+(qy-ay)*(qy-ay)+(qz-az)*(qz-az));
    float dB = sqrtf((nx-bx)*(nx-bx)+(ny-by)*(ny-by)+(nz-bz)*(nz-bz));
    float dAB = adist[(size_t)b*MA*MA + mi*MA + bj];
    float r2 = dA + dAB + dB;
    s_feat[w][0][kk] = fabsf(r1x); s_feat[w][1][kk] = fabsf(r1y); s_feat[w][2][kk] = fabsf(r1z);
    s_feat[w][3][kk] = r2; s_feat[w][4][kk] = r2; s_feat[w][5][kk] = r2;
  }
  __syncthreads();

  // ---- P1: h1 = relu(lw1 @ feats) (32x16 per point) ----
  {
    float f0=s_feat[w][0][k], f1=s_feat[w][1][k], f2=s_feat[w][2][k],
          f3=s_feat[w][3][k], f4=s_feat[w][4][k], f5=s_feat[w][5][k];
#pragma unroll
    for (int jj = 0; jj < 8; jj++) {
      int h = g*8 + jj;
      const float* wp = lw1f + h*6;
      float v = wp[0]*f0 + wp[1]*f1 + wp[2]*f2 + wp[3]*f3 + wp[4]*f4 + wp[5]*f5;
      s_h1[w][h][k] = f2u(fmaxf(v, 0.f));
    }
  }
  __syncthreads();

  // ---- P2: h2 = relu(lw2 @ h1) -> H[col][0..64); P2.5: ph -> H[col][64..128) ----
  {
    float hr[32];
#pragma unroll
    for (int t = 0; t < 32; t++) hr[t] = u2f(s_h1[w][t][k]);
#pragma unroll
    for (int jj = 0; jj < 16; jj++) {
      int h = g*16 + jj;
      const float4* wp = (const float4*)(lw2f + h*32);
      float a = 0.f;
#pragma unroll
      for (int t4 = 0; t4 < 8; t4++) {
        float4 wv = wp[t4];
        a += wv.x*hr[t4*4] + wv.y*hr[t4*4+1] + wv.z*hr[t4*4+2] + wv.w*hr[t4*4+3];
      }
      st1(hid_t, col_w, h, 8, fmaxf(a, 0.f));
    }
    float pr0 = s_prel[w][0][k], pr1 = s_prel[w][1][k], pr2 = s_prel[w][2][k];
#pragma unroll
    for (int jj = 0; jj < 16; jj++) {
      int h = g*16 + jj;
      float d = pw1f[h*3]*pr0 + pw1f[h*3+1]*pr1 + pw1f[h*3+2]*pr2;
      st1(hid_t, col_w, 64 + h, 8, fmaxf(d*spv[h] + opv[h], 0.f));
    }
  }
  __syncthreads();

  // ---- s-build: s = (q - k_g + pb2) + W' @ H  via MFMA, write s_t bf16 ----
  {
    f32x4 accs[4][4];
#pragma unroll
    for (int fr = 0; fr < 4; fr++) {
      int ch0 = w*64 + fr*16 + g*4;
      const float4 p4 = *(const float4*)(pb2f + ch0);
#pragma unroll
      for (int fc = 0; fc < 4; fc++) {
        int j = s_idx[fc][k];
        const float4 q4 = *(const float4*)(qB + (size_t)(pi0 + fc)*DC + ch0);
        const float4 k4 = *(const float4*)(kB + (size_t)j*DC + ch0);
        accs[fr][fc][0] = q4.x - k4.x + p4.x;
        accs[fr][fc][1] = q4.y - k4.y + p4.y;
        accs[fr][fc][2] = q4.z - k4.z + p4.z;
        accs[fr][fc][3] = q4.w - k4.w + p4.w;
      }
    }
#pragma unroll
    for (int ks = 0; ks < 4; ks++) {
      s8v aF[4];
#pragma unroll
      for (int fr = 0; fr < 4; fr++) aF[fr] = ldpk(wppk, w*4 + fr, 4, ks, l);
#pragma unroll
      for (int fc = 0; fc < 4; fc++) {
        s8v bF = ldsB(hid_t, fc*16 + k, ks*32 + g*8, 8);
#pragma unroll
        for (int fr = 0; fr < 4; fr++) accs[fr][fc] = MFMA_B16(aF[fr], bF, accs[fr][fc]);
      }
    }
#pragma unroll
    for (int fr = 0; fr < 4; fr++)
#pragma unroll
      for (int fc = 0; fc < 4; fc++)
        st2(s_t, fc*16 + k, w*64 + fr*16 + g*4, 9,
            accs[fr][fc][0], accs[fr][fc][1], accs[fr][fc][2], accs[fr][fc][3]);
  }
  __syncthreads();

  // ---- attention MLP: 8 chunks of 128 hidden ----
  f32x4 acc2[4][4];
#pragma unroll
  for (int fr = 0; fr < 4; fr++) {
    const float4 a4 = *(const float4*)(ab2f + w*64 + fr*16 + g*4);
#pragma unroll
    for (int fc = 0; fc < 4; fc++) {
      acc2[fr][fc][0] = a4.x; acc2[fr][fc][1] = a4.y;
      acc2[fr][fc][2] = a4.z; acc2[fr][fc][3] = a4.w;
    }
  }

  for (int c = 0; c < 8; c++) {
    // layer 1: rows [c*128 + w*32, +32), K=256 over s_t
    f32x4 acc1[2][4] = {};
    int rb0 = c*8 + w*2;
#pragma unroll
    for (int ks = 0; ks < 8; ks++) {
      s8v a0 = ldpk(aw1pk, rb0,     8, ks, l);
      s8v a1 = ldpk(aw1pk, rb0 + 1, 8, ks, l);
#pragma unroll
      for (int cf = 0; cf < 4; cf++) {
        s8v bF = ldsB(s_t, cf*16 + k, ks*32 + g*8, 9);
        acc1[0][cf] = MFMA_B16(a0, bF, acc1[0][cf]);
        acc1[1][cf] = MFMA_B16(a1, bF, acc1[1][cf]);
      }
    }
    __syncthreads();   // previous chunk's layer-2 / s-build H reads done
#pragma unroll
    for (int ri = 0; ri < 2; ri++) {
      int hl = w*32 + ri*16 + g*4;
      int hg = c*128 + hl;
      const float4 sc = *(const float4*)(sav + hg);
      const float4 of = *(const float4*)(oav + hg);
#pragma unroll
      for (int cf = 0; cf < 4; cf++) {
        float v0 = fmaxf(acc1[ri][cf][0]*sc.x + of.x, 0.f);
        float v1 = fmaxf(acc1[ri][cf][1]*sc.y + of.y, 0.f);
        float v2 = fmaxf(acc1[ri][cf][2]*sc.z + of.z, 0.f);
        float v3 = fmaxf(acc1[ri][cf][3]*sc.w + of.w, 0.f);
        st2(hid_t, cf*16 + k, hl, 8, v0, v1, v2, v3);
      }
    }
    __syncthreads();   // hid chunk ready
    // layer 2: K=128 over hid_t
#pragma unroll
    for (int ks = 0; ks < 4; ks++) {
      s8v aF[4];
#pragma unroll
      for (int rf = 0; rf < 4; rf++) aF[rf] = ldpk(aw2pk, w*4 + rf, 32, c*4 + ks, l);
#pragma unroll
      for (int cf = 0; cf < 4; cf++) {
        s8v bF = ldsB(hid_t, cf*16 + k, ks*32 + g*8, 8);
#pragma unroll
        for (int rf = 0; rf < 4; rf++) acc2[rf][cf] = MFMA_B16(aF[rf], bF, acc2[rf][cf]);
      }
    }
  }

  // ---- softmax over k (width-16 xor) + aggregation ----
#pragma unroll
  for (int fc = 0; fc < 4; fc++) {
    int j = s_idx[fc][k];
    const float* qp = qB + (size_t)(pi0 + fc)*DC;
    const float* kp = kB + (size_t)j*DC;
    const float* vp = vB + (size_t)(pi0 + fc)*DC;
#pragma unroll
    for (int fr = 0; fr < 4; fr++) {
      int ch0 = w*64 + fr*16 + g*4;
      float q4[4], k4[4], v4[4], s4[4], res[4];
      *(float4*)q4 = *(const float4*)(qp + ch0);
      *(float4*)k4 = *(const float4*)(kp + ch0);
      *(float4*)v4 = *(const float4*)(vp + ch0);
      ld4s(s_t, fc*16 + k, ch0, 9, s4);
#pragma unroll
      for (int r = 0; r < 4; r++) {
        float a = acc2[fr][fc][r];
        float m = a;
        m = fmaxf(m, __shfl_xor(m, 1, 16)); m = fmaxf(m, __shfl_xor(m, 2, 16));
        m = fmaxf(m, __shfl_xor(m, 4, 16)); m = fmaxf(m, __shfl_xor(m, 8, 16));
        float ex = __expf(a - m);
        float se = ex;
        se += __shfl_xor(se, 1, 16); se += __shfl_xor(se, 2, 16);
        se += __shfl_xor(se, 4, 16); se += __shfl_xor(se, 8, 16);
        float watt = ex / se;
        float ve = v4[r] - q4[r] + k4[r] + s4[r];   // value + pos_emb + f_l
        float cc = watt * ve;
        cc += __shfl_xor(cc, 1, 16); cc += __shfl_xor(cc, 2, 16);
        cc += __shfl_xor(cc, 4, 16); cc += __shfl_xor(cc, 8, 16);
        res[r] = cc;
      }
      if (k == 0)
        *(float4*)(aggT + ((size_t)(b*NP) + pi0 + fc)*DC + ch0) =
            make_float4(res[0], res[1], res[2], res[3]);
    }
  }
}

// ---------------- launch ----------------
extern "C" void kernel_launch(void* const* d_in, const int* in_sizes, int n_in,
                              void* d_out, int out_size, void* d_ws, size_t ws_size,
                              hipStream_t stream)
{
  const float* x        = (const float*)d_in[0];
  const float* pos      = (const float*)d_in[1];
  const float* P_anchor = (const float*)d_in[3];
  const int*   map_idx  = (const int*)  d_in[4];
  const float* adist    = (const float*)d_in[5];
  const float* w_start  = (const float*)d_in[6];
  const float* b_start  = (const float*)d_in[7];
  const float* w_key    = (const float*)d_in[8];
  const float* b_key    = (const float*)d_in[9];
  const float* w_query  = (const float*)d_in[10];
  const float* b_query  = (const float*)d_in[11];
  const float* w_value  = (const float*)d_in[12];
  const float* b_value  = (const float*)d_in[13];
  const float* pw1      = (const float*)d_in[14];
  const float* pb1      = (const float*)d_in[15];
  const float* pg1      = (const float*)d_in[16];
  const float* pbt1     = (const float*)d_in[17];
  const float* pw2      = (const float*)d_in[18];
  const float* pb2      = (const float*)d_in[19];
  const float* lw1      = (const float*)d_in[20];
  const float* lw2      = (const float*)d_in[21];
  const float* lw3      = (const float*)d_in[22];
  const float* aw1      = (const float*)d_in[23];
  const float* ab1      = (const float*)d_in[24];
  const float* ag1      = (const float*)d_in[25];
  const float* abt1     = (const float*)d_in[26];
  const float* aw2      = (const float*)d_in[27];
  const float* ab2      = (const float*)d_in[28];
  const float* w_end    = (const float*)d_in[29];
  const float* b_end    = (const float*)d_in[30];

  if (ws_size < (size_t)4802688 * 4) return;   // 19.2 MB

  float* ws     = (float*)d_ws;
  float* xf     = ws + 0;            // 1048576 floats; later reused as aggT
  float* aggT   = ws + 0;
  float* keyT   = ws + 1048576;
  float* queryT = ws + 2097152;
  float* valueT = ws + 3145728;
  u16*   aw1pk  = (u16*)(ws + 4194304);  // 262144 floats
  u16*   aw2pk  = (u16*)(ws + 4456448);  // 262144 floats
  u16*   wppk   = (u16*)(ws + 4718592);  // 16384 floats
  float* sa     = ws + 4734976;
  float* oa     = ws + 4736000;
  float* sp     = ws + 4737024;
  float* op_    = ws + 4737088;
  int*   knn_i  = (int*)(ws + 4737152);  // 65536 ints
  // end: 4802688 floats

  prep_kernel<<<2181, 256, 0, stream>>>(aw1, aw2, lw3, pw2,
      ag1, ab1, abt1, pg1, pb1, pbt1,
      aw1pk, aw2pk, wppk, sa, oa, sp, op_);

  gemm_k<false, false, false><<<dim3(32,4,2), 256, 0, stream>>>(
      w_start, x, b_start, nullptr, xf, 256, NP, 128);

  knn_kernel<<<64, 64, 0, stream>>>(pos, knn_i);

  gemm_k<false, true, false><<<dim3(32,4,2), 256, 0, stream>>>(
      w_key,   xf, b_key,   nullptr, keyT,   256, NP, 256);
  gemm_k<false, true, false><<<dim3(32,4,2), 256, 0, stream>>>(
      w_query, xf, b_query, nullptr, queryT, 256, NP, 256);
  gemm_k<false, true, false><<<dim3(32,4,2), 256, 0, stream>>>(
      w_value, xf, b_value, nullptr, valueT, 256, NP, 256);

  fused_attn<<<1024, 256, 0, stream>>>(keyT, queryT, valueT, knn_i,
      pos, map_idx, P_anchor, adist,
      lw1, lw2, pw1, sp, op_, pb2,
      aw1pk, sa, oa, aw2pk, wppk, ab2, aggT);

  gemm_k<true, false, true><<<dim3(32,2,2), 256, 0, stream>>>(
      w_end, aggT, b_end, x, (float*)d_out, 128, NP, 256);
}

// Round 4
// 322.942 us; speedup vs baseline: 19.4499x; 3.4866x over previous
//
#include <hip/hip_runtime.h>
#include <hip/hip_bf16.h>

typedef __hip_bfloat16 bf16;
typedef unsigned short u16;
typedef __attribute__((ext_vector_type(8))) short s8v;    // 8 bf16 (4 VGPRs) MFMA frag
typedef __attribute__((ext_vector_type(4))) float f32x4;  // MFMA acc frag

#define NP    2048
#define DC    256
#define MA    128
#define KNN_  16

#define MFMA_B16(a,b,c) __builtin_amdgcn_mfma_f32_16x16x32_bf16(a,b,c,0,0,0)

__device__ __forceinline__ float u2f(u16 u){ return __uint_as_float(((unsigned int)u)<<16); }
__device__ __forceinline__ u16 f2u(float f){ bf16 h=__float2bfloat16(f); u16 us; __builtin_memcpy(&us,&h,2); return us; }

// packed A-frag load: layout [((rb*KS+ks)*64+l)*8 + j]
__device__ __forceinline__ s8v ldpk(const u16* pk, int rb, int KS, int ks, int l){
  return *(const s8v*)(pk + (((size_t)((rb*KS + ks)*64 + l))<<3));
}
// LDS B-frag read, 16B, XOR-swizzled. rshift = log2(row bytes)
__device__ __forceinline__ s8v ldsB(const u16* base, int col, int k0, int rshift){
  int byte = ((col<<rshift) + (k0<<1)) ^ ((col&7)<<4);
  return *(const s8v*)((const char*)base + byte);
}
// LDS 4x bf16 write (8B), swizzled
__device__ __forceinline__ void st2(u16* base, int col, int ch0, int rshift,
                                    float v0, float v1, float v2, float v3){
  uint2 pkv;
  pkv.x = (unsigned)f2u(v0) | ((unsigned)f2u(v1)<<16);
  pkv.y = (unsigned)f2u(v2) | ((unsigned)f2u(v3)<<16);
  int byte = ((col<<rshift) + (ch0<<1)) ^ ((col&7)<<4);
  *(uint2*)((char*)base + byte) = pkv;
}
// LDS single bf16 write, swizzled
__device__ __forceinline__ void st1(u16* base, int col, int ch, int rshift, float v){
  int byte = ((col<<rshift) + (ch<<1)) ^ ((col&7)<<4);
  *(u16*)((char*)base + byte) = f2u(v);
}
// LDS 4x bf16 read (8B), swizzled
__device__ __forceinline__ void ld4s(const u16* base, int col, int ch0, int rshift, float* o){
  int byte = ((col<<rshift) + (ch0<<1)) ^ ((col&7)<<4);
  uint2 pkv = *(const uint2*)((const char*)base + byte);
  o[0] = u2f(pkv.x & 0xffff); o[1] = u2f(pkv.x>>16);
  o[2] = u2f(pkv.y & 0xffff); o[3] = u2f(pkv.y>>16);
}

// ---------------- generic small GEMM (f32 vector path) ----------------
template<bool XT, bool OT, bool RES>
__global__ __launch_bounds__(256) void gemm_k(
    const float* __restrict__ W, const float* __restrict__ X,
    const float* __restrict__ bias, const float* __restrict__ resid,
    float* __restrict__ out, int M, int N, int K)
{
  __shared__ float Ws[16][65];
  __shared__ float Xs[16][65];
  const int tid = threadIdx.x;
  const int tx = tid & 15, ty = tid >> 4;
  const int n0 = blockIdx.x * 64, m0 = blockIdx.y * 64, bb = blockIdx.z;
  float c[4][4] = {};
  for (int k0 = 0; k0 < K; k0 += 16) {
#pragma unroll
    for (int ldi = 0; ldi < 4; ldi++) {
      int e = tid + ldi * 256;
      int m = e >> 4, kk = e & 15;
      Ws[kk][m] = W[(size_t)(m0 + m) * K + k0 + kk];
    }
#pragma unroll
    for (int ldi = 0; ldi < 4; ldi++) {
      int e = tid + ldi * 256;
      if constexpr (!XT) {
        int kk = e >> 6, nn = e & 63;
        Xs[kk][nn] = X[(size_t)bb * K * N + (size_t)(k0 + kk) * N + n0 + nn];
      } else {
        int nn = e >> 4, kk = e & 15;
        Xs[kk][nn] = X[(size_t)bb * N * K + (size_t)(n0 + nn) * K + k0 + kk];
      }
    }
    __syncthreads();
#pragma unroll
    for (int kk = 0; kk < 16; kk++) {
      float av[4], bv[4];
#pragma unroll
      for (int q = 0; q < 4; q++) { av[q] = Ws[kk][ty*4+q]; bv[q] = Xs[kk][tx*4+q]; }
#pragma unroll
      for (int q = 0; q < 4; q++)
#pragma unroll
        for (int r = 0; r < 4; r++) c[q][r] += av[q] * bv[r];
    }
    __syncthreads();
  }
#pragma unroll
  for (int q = 0; q < 4; q++) {
    int m = m0 + ty*4 + q;
    float bsv = bias[m];
#pragma unroll
    for (int r = 0; r < 4; r++) {
      int n = n0 + tx*4 + r;
      float v = c[q][r] + bsv;
      if constexpr (RES) v += resid[(size_t)bb * M * N + (size_t)m * N + n];
      if constexpr (!OT) out[(size_t)bb * M * N + (size_t)m * N + n] = v;
      else               out[(size_t)bb * N * M + (size_t)n * M + m] = v;
    }
  }
}

// ---------------- KNN top-16: wave-per-query, static-index only (no scratch) ----------
// block = 1024 threads = 16 waves = 16 queries; lane l scans j = t*64+l.
__global__ __launch_bounds__(1024) void knn_kernel(const float* __restrict__ pos, int* __restrict__ idx)
{
  __shared__ float px[NP], py[NP], pz[NP], pn[NP];
  const int tid = threadIdx.x;
  const int w = tid >> 6, l = tid & 63;
  const int bb = blockIdx.x >> 7;          // 128 blocks per batch
  const int q0 = (blockIdx.x & 127) * 16;
  const float* pp = pos + (size_t)bb * 3 * NP;
  for (int t = tid; t < NP; t += 1024) {
    float x = pp[t], y = pp[NP + t], z = pp[2*NP + t];
    px[t] = x; py[t] = y; pz[t] = z; pn[t] = x*x + y*y + z*z;
  }
  __syncthreads();
  const int qi = q0 + w;
  const float qx = px[qi], qy = py[qi], qz = pz[qi], qn = pn[qi];

  // per-lane sorted top-16 over this lane's 32 candidates (branch-free bubble insert)
  float bd[16]; int bi[16];
#pragma unroll
  for (int t = 0; t < 16; t++) { bd[t] = 3.4e38f; bi[t] = -1; }
  float worst = 3.4e38f;
  for (int t = 0; t < 32; t++) {
    int j = t*64 + l;
    float d = qn + pn[j] - 2.f * (qx*px[j] + qy*py[j] + qz*pz[j]);
    if (__any(d < worst)) {
      float cd = (d < worst) ? d : 3.4e38f;   // inactive lanes bubble a no-op sentinel
      int   cj = j;
#pragma unroll
      for (int s = 0; s < 16; s++) {
        bool sw = cd < bd[s];                  // strict <: equal keeps earlier j (stable)
        float od = bd[s]; int oj = bi[s];
        bd[s] = sw ? cd : od;  bi[s] = sw ? cj : oj;
        cd    = sw ? od : cd;  cj    = sw ? oj : cj;
      }
      worst = bd[15];
    }
  }

  // merge 64 sorted lists: 16 rounds of wave-argmin (lexicographic (d, j)) + pop winner
  int myj = 0;
#pragma unroll
  for (int r = 0; r < 16; r++) {
    float md = bd[0]; int mj = bi[0];
#pragma unroll
    for (int o = 1; o < 64; o <<= 1) {
      float od = __shfl_xor(md, o);
      int   oj = __shfl_xor(mj, o);
      bool tk = (od < md) || (od == md && ((unsigned)oj < (unsigned)mj));
      md = tk ? od : md;  mj = tk ? oj : mj;
    }
    if (l == r) myj = mj;                      // round r's winner -> lane r (static r)
    bool win = (bi[0] == mj);                  // j unique across lanes
#pragma unroll
    for (int s = 0; s < 15; s++) {
      bd[s] = win ? bd[s+1] : bd[s];
      bi[s] = win ? bi[s+1] : bi[s];
    }
    bd[15] = win ? 3.4e38f : bd[15];
  }
  if (l < 16) idx[((size_t)bb * NP + qi) * KNN_ + l] = myj;
}

// ---------------- prep: pack MFMA A-fragments (bf16) + BN folds ----------------
__global__ __launch_bounds__(256) void prep_kernel(
    const float* __restrict__ aw1, const float* __restrict__ aw2,
    const float* __restrict__ lw3, const float* __restrict__ pw2,
    const float* __restrict__ ag1, const float* __restrict__ ab1, const float* __restrict__ abt1,
    const float* __restrict__ pg1, const float* __restrict__ pb1, const float* __restrict__ pbt1,
    u16* __restrict__ aw1pk, u16* __restrict__ aw2pk, u16* __restrict__ wppk,
    float* __restrict__ sa, float* __restrict__ oa, float* __restrict__ sp, float* __restrict__ op_)
{
  int i = blockIdx.x * 256 + threadIdx.x;
  const float inv = rsqrtf(1.0f + 1e-5f);
  if (i < 262144) {  // aw1 (1024x256), KS=8, rb-stride 4096
    int rb = i >> 12, rem = i & 4095, ks = rem >> 9, l = (rem >> 3) & 63, j = rem & 7;
    int row = rb*16 + (l & 15), colk = ks*32 + (l >> 4)*8 + j;
    aw1pk[i] = f2u(aw1[(size_t)row*256 + colk]); return;
  }
  i -= 262144;
  if (i < 262144) {  // aw2 (256x1024), KS=32, rb-stride 16384
    int rb = i >> 14, rem = i & 16383, ks = rem >> 9, l = (rem >> 3) & 63, j = rem & 7;
    int row = rb*16 + (l & 15), colk = ks*32 + (l >> 4)*8 + j;
    aw2pk[i] = f2u(aw2[(size_t)row*1024 + colk]); return;
  }
  i -= 262144;
  if (i < 32768) {   // W' = [lw3 | pw2] (256x128), KS=4, rb-stride 2048
    int rb = i >> 11, rem = i & 2047, ks = rem >> 9, l = (rem >> 3) & 63, j = rem & 7;
    int row = rb*16 + (l & 15), colk = ks*32 + (l >> 4)*8 + j;
    float v = (colk < 64) ? lw3[row*64 + colk] : pw2[row*64 + (colk - 64)];
    wppk[i] = f2u(v); return;
  }
  i -= 32768;
  if (i < 1024) { float s_ = ag1[i]*inv; sa[i] = s_; oa[i] = ab1[i]*s_ + abt1[i]; return; }
  i -= 1024;
  if (i < 64)  { float s_ = pg1[i]*inv; sp[i] = s_; op_[i] = pb1[i]*s_ + pbt1[i]; return; }
}

// ---------------- fused: geometric MLPs + MFMA attention MLP + softmax + agg ----------
// block = 4 waves = 4 points = 64 (point,k) columns
__global__ __launch_bounds__(256, 2) void fused_attn(
    const float* __restrict__ keyT, const float* __restrict__ queryT,
    const float* __restrict__ valueT, const int* __restrict__ knn_idx,
    const float* __restrict__ pos, const int* __restrict__ map_idx,
    const float* __restrict__ P_anchor, const float* __restrict__ adist,
    const float* __restrict__ lw1f, const float* __restrict__ lw2f, const float* __restrict__ pw1f,
    const float* __restrict__ spv, const float* __restrict__ opv, const float* __restrict__ pb2f,
    const u16* __restrict__ aw1pk, const float* __restrict__ sav, const float* __restrict__ oav,
    const u16* __restrict__ aw2pk, const u16* __restrict__ wppk, const float* __restrict__ ab2f,
    float* __restrict__ aggT)
{
  __shared__ u16 s_t[64*256];     // s tile [col][ch], bf16, XOR-swizzled (row=512B)
  __shared__ u16 hid_t[64*128];   // H (geom hidden) then hid chunks [col][kk] (row=256B)
  __shared__ u16 s_h1[4][32][17];
  __shared__ float s_feat[4][6][17];
  __shared__ float s_prel[4][3][17];
  __shared__ int   s_idx[4][16];

  const int tid = threadIdx.x;
  const int w = tid >> 6, l = tid & 63;
  const int k = l & 15, g = l >> 4;
  const int p0 = blockIdx.x * 4;
  const int b = p0 >> 11, pi0 = p0 & 2047;
  const int pi = pi0 + w;            // phase-1: wave w owns point pi
  const int col_w = w*16 + k;        // phase-1 column

  const float* qB = queryT + ((size_t)b * NP) * DC;
  const float* kB = keyT   + ((size_t)b * NP) * DC;
  const float* vB = valueT + ((size_t)b * NP) * DC;

  // ---- P0: geometric features (16 lanes per wave) ----
  if (l < 16) {
    int kk = l;
    int j = knn_idx[((size_t)(b*NP) + pi) * KNN_ + kk];
    s_idx[w][kk] = j;
    const float* pp = pos + (size_t)b * 3 * NP;
    float qx = pp[pi], qy = pp[NP+pi], qz = pp[2*NP+pi];
    float nx = pp[j],  ny = pp[NP+j],  nz = pp[2*NP+j];
    float r1x = qx-nx, r1y = qy-ny, r1z = qz-nz;
    s_prel[w][0][kk] = r1x; s_prel[w][1][kk] = r1y; s_prel[w][2][kk] = r1z;
    int mi = map_idx[b*NP + pi];
    int bj = map_idx[b*NP + j];
    const float* pa = P_anchor + (size_t)b * MA * 3;
    float ax = pa[mi*3], ay = pa[mi*3+1], az = pa[mi*3+2];
    float bx = pa[bj*3], by = pa[bj*3+1], bz = pa[bj*3+2];
    float dA = sqrtf((qx-ax)*(qx-ax)+(qy-ay)*(qy-ay)+(qz-az)*(qz-az));
    float dB = sqrtf((nx-bx)*(nx-bx)+(ny-by)*(ny-by)+(nz-bz)*(nz-bz));
    float dAB = adist[(size_t)b*MA*MA + mi*MA + bj];
    float r2 = dA + dAB + dB;
    s_feat[w][0][kk] = fabsf(r1x); s_feat[w][1][kk] = fabsf(r1y); s_feat[w][2][kk] = fabsf(r1z);
    s_feat[w][3][kk] = r2; s_feat[w][4][kk] = r2; s_feat[w][5][kk] = r2;
  }
  __syncthreads();

  // ---- P1: h1 = relu(lw1 @ feats) (32x16 per point) ----
  {
    float f0=s_feat[w][0][k], f1=s_feat[w][1][k], f2=s_feat[w][2][k],
          f3=s_feat[w][3][k], f4=s_feat[w][4][k], f5=s_feat[w][5][k];
#pragma unroll
    for (int jj = 0; jj < 8; jj++) {
      int h = g*8 + jj;
      const float* wp = lw1f + h*6;
      float v = wp[0]*f0 + wp[1]*f1 + wp[2]*f2 + wp[3]*f3 + wp[4]*f4 + wp[5]*f5;
      s_h1[w][h][k] = f2u(fmaxf(v, 0.f));
    }
  }
  __syncthreads();

  // ---- P2: h2 = relu(lw2 @ h1) -> H[col][0..64); P2.5: ph -> H[col][64..128) ----
  {
    float hr[32];
#pragma unroll
    for (int t = 0; t < 32; t++) hr[t] = u2f(s_h1[w][t][k]);
#pragma unroll
    for (int jj = 0; jj < 16; jj++) {
      int h = g*16 + jj;
      const float4* wp = (const float4*)(lw2f + h*32);
      float a = 0.f;
#pragma unroll
      for (int t4 = 0; t4 < 8; t4++) {
        float4 wv = wp[t4];
        a += wv.x*hr[t4*4] + wv.y*hr[t4*4+1] + wv.z*hr[t4*4+2] + wv.w*hr[t4*4+3];
      }
      st1(hid_t, col_w, h, 8, fmaxf(a, 0.f));
    }
    float pr0 = s_prel[w][0][k], pr1 = s_prel[w][1][k], pr2 = s_prel[w][2][k];
#pragma unroll
    for (int jj = 0; jj < 16; jj++) {
      int h = g*16 + jj;
      float d = pw1f[h*3]*pr0 + pw1f[h*3+1]*pr1 + pw1f[h*3+2]*pr2;
      st1(hid_t, col_w, 64 + h, 8, fmaxf(d*spv[h] + opv[h], 0.f));
    }
  }
  __syncthreads();

  // ---- s-build: s = (q - k_g + pb2) + W' @ H  via MFMA, write s_t bf16 ----
  {
    f32x4 accs[4][4];
#pragma unroll
    for (int fr = 0; fr < 4; fr++) {
      int ch0 = w*64 + fr*16 + g*4;
      const float4 p4 = *(const float4*)(pb2f + ch0);
#pragma unroll
      for (int fc = 0; fc < 4; fc++) {
        int j = s_idx[fc][k];
        const float4 q4 = *(const float4*)(qB + (size_t)(pi0 + fc)*DC + ch0);
        const float4 k4 = *(const float4*)(kB + (size_t)j*DC + ch0);
        accs[fr][fc][0] = q4.x - k4.x + p4.x;
        accs[fr][fc][1] = q4.y - k4.y + p4.y;
        accs[fr][fc][2] = q4.z - k4.z + p4.z;
        accs[fr][fc][3] = q4.w - k4.w + p4.w;
      }
    }
#pragma unroll
    for (int ks = 0; ks < 4; ks++) {
      s8v aF[4];
#pragma unroll
      for (int fr = 0; fr < 4; fr++) aF[fr] = ldpk(wppk, w*4 + fr, 4, ks, l);
#pragma unroll
      for (int fc = 0; fc < 4; fc++) {
        s8v bF = ldsB(hid_t, fc*16 + k, ks*32 + g*8, 8);
#pragma unroll
        for (int fr = 0; fr < 4; fr++) accs[fr][fc] = MFMA_B16(aF[fr], bF, accs[fr][fc]);
      }
    }
#pragma unroll
    for (int fr = 0; fr < 4; fr++)
#pragma unroll
      for (int fc = 0; fc < 4; fc++)
        st2(s_t, fc*16 + k, w*64 + fr*16 + g*4, 9,
            accs[fr][fc][0], accs[fr][fc][1], accs[fr][fc][2], accs[fr][fc][3]);
  }
  __syncthreads();

  // ---- attention MLP: 8 chunks of 128 hidden ----
  f32x4 acc2[4][4];
#pragma unroll
  for (int fr = 0; fr < 4; fr++) {
    const float4 a4 = *(const float4*)(ab2f + w*64 + fr*16 + g*4);
#pragma unroll
    for (int fc = 0; fc < 4; fc++) {
      acc2[fr][fc][0] = a4.x; acc2[fr][fc][1] = a4.y;
      acc2[fr][fc][2] = a4.z; acc2[fr][fc][3] = a4.w;
    }
  }

  for (int c = 0; c < 8; c++) {
    // layer 1: rows [c*128 + w*32, +32), K=256 over s_t
    f32x4 acc1[2][4] = {};
    int rb0 = c*8 + w*2;
#pragma unroll
    for (int ks = 0; ks < 8; ks++) {
      s8v a0 = ldpk(aw1pk, rb0,     8, ks, l);
      s8v a1 = ldpk(aw1pk, rb0 + 1, 8, ks, l);
#pragma unroll
      for (int cf = 0; cf < 4; cf++) {
        s8v bF = ldsB(s_t, cf*16 + k, ks*32 + g*8, 9);
        acc1[0][cf] = MFMA_B16(a0, bF, acc1[0][cf]);
        acc1[1][cf] = MFMA_B16(a1, bF, acc1[1][cf]);
      }
    }
    __syncthreads();   // previous chunk's layer-2 / s-build H reads done
#pragma unroll
    for (int ri = 0; ri < 2; ri++) {
      int hl = w*32 + ri*16 + g*4;
      int hg = c*128 + hl;
      const float4 sc = *(const float4*)(sav + hg);
      const float4 of = *(const float4*)(oav + hg);
#pragma unroll
      for (int cf = 0; cf < 4; cf++) {
        float v0 = fmaxf(acc1[ri][cf][0]*sc.x + of.x, 0.f);
        float v1 = fmaxf(acc1[ri][cf][1]*sc.y + of.y, 0.f);
        float v2 = fmaxf(acc1[ri][cf][2]*sc.z + of.z, 0.f);
        float v3 = fmaxf(acc1[ri][cf][3]*sc.w + of.w, 0.f);
        st2(hid_t, cf*16 + k, hl, 8, v0, v1, v2, v3);
      }
    }
    __syncthreads();   // hid chunk ready
    // layer 2: K=128 over hid_t
#pragma unroll
    for (int ks = 0; ks < 4; ks++) {
      s8v aF[4];
#pragma unroll
      for (int rf = 0; rf < 4; rf++) aF[rf] = ldpk(aw2pk, w*4 + rf, 32, c*4 + ks, l);
#pragma unroll
      for (int cf = 0; cf < 4; cf++) {
        s8v bF = ldsB(hid_t, cf*16 + k, ks*32 + g*8, 8);
#pragma unroll
        for (int rf = 0; rf < 4; rf++) acc2[rf][cf] = MFMA_B16(aF[rf], bF, acc2[rf][cf]);
      }
    }
  }

  // ---- softmax over k (width-16 xor) + aggregation ----
#pragma unroll
  for (int fc = 0; fc < 4; fc++) {
    int j = s_idx[fc][k];
    const float* qp = qB + (size_t)(pi0 + fc)*DC;
    const float* kp = kB + (size_t)j*DC;
    const float* vp = vB + (size_t)(pi0 + fc)*DC;
#pragma unroll
    for (int fr = 0; fr < 4; fr++) {
      int ch0 = w*64 + fr*16 + g*4;
      float q4[4], k4[4], v4[4], s4[4], res[4];
      *(float4*)q4 = *(const float4*)(qp + ch0);
      *(float4*)k4 = *(const float4*)(kp + ch0);
      *(float4*)v4 = *(const float4*)(vp + ch0);
      ld4s(s_t, fc*16 + k, ch0, 9, s4);
#pragma unroll
      for (int r = 0; r < 4; r++) {
        float a = acc2[fr][fc][r];
        float m = a;
        m = fmaxf(m, __shfl_xor(m, 1, 16)); m = fmaxf(m, __shfl_xor(m, 2, 16));
        m = fmaxf(m, __shfl_xor(m, 4, 16)); m = fmaxf(m, __shfl_xor(m, 8, 16));
        float ex = __expf(a - m);
        float se = ex;
        se += __shfl_xor(se, 1, 16); se += __shfl_xor(se, 2, 16);
        se += __shfl_xor(se, 4, 16); se += __shfl_xor(se, 8, 16);
        float watt = ex / se;
        float ve = v4[r] - q4[r] + k4[r] + s4[r];   // value + pos_emb + f_l
        float cc = watt * ve;
        cc += __shfl_xor(cc, 1, 16); cc += __shfl_xor(cc, 2, 16);
        cc += __shfl_xor(cc, 4, 16); cc += __shfl_xor(cc, 8, 16);
        res[r] = cc;
      }
      if (k == 0)
        *(float4*)(aggT + ((size_t)(b*NP) + pi0 + fc)*DC + ch0) =
            make_float4(res[0], res[1], res[2], res[3]);
    }
  }
}

// ---------------- launch ----------------
extern "C" void kernel_launch(void* const* d_in, const int* in_sizes, int n_in,
                              void* d_out, int out_size, void* d_ws, size_t ws_size,
                              hipStream_t stream)
{
  const float* x        = (const float*)d_in[0];
  const float* pos      = (const float*)d_in[1];
  const float* P_anchor = (const float*)d_in[3];
  const int*   map_idx  = (const int*)  d_in[4];
  const float* adist    = (const float*)d_in[5];
  const float* w_start  = (const float*)d_in[6];
  const float* b_start  = (const float*)d_in[7];
  const float* w_key    = (const float*)d_in[8];
  const float* b_key    = (const float*)d_in[9];
  const float* w_query  = (const float*)d_in[10];
  const float* b_query  = (const float*)d_in[11];
  const float* w_value  = (const float*)d_in[12];
  const float* b_value  = (const float*)d_in[13];
  const float* pw1      = (const float*)d_in[14];
  const float* pb1      = (const float*)d_in[15];
  const float* pg1      = (const float*)d_in[16];
  const float* pbt1     = (const float*)d_in[17];
  const float* pw2      = (const float*)d_in[18];
  const float* pb2      = (const float*)d_in[19];
  const float* lw1      = (const float*)d_in[20];
  const float* lw2      = (const float*)d_in[21];
  const float* lw3      = (const float*)d_in[22];
  const float* aw1      = (const float*)d_in[23];
  const float* ab1      = (const float*)d_in[24];
  const float* ag1      = (const float*)d_in[25];
  const float* abt1     = (const float*)d_in[26];
  const float* aw2      = (const float*)d_in[27];
  const float* ab2      = (const float*)d_in[28];
  const float* w_end    = (const float*)d_in[29];
  const float* b_end    = (const float*)d_in[30];

  if (ws_size < (size_t)4802688 * 4) return;   // 19.2 MB

  float* ws     = (float*)d_ws;
  float* xf     = ws + 0;            // 1048576 floats; later reused as aggT
  float* aggT   = ws + 0;
  float* keyT   = ws + 1048576;
  float* queryT = ws + 2097152;
  float* valueT = ws + 3145728;
  u16*   aw1pk  = (u16*)(ws + 4194304);  // 262144 floats
  u16*   aw2pk  = (u16*)(ws + 4456448);  // 262144 floats
  u16*   wppk   = (u16*)(ws + 4718592);  // 16384 floats
  float* sa     = ws + 4734976;
  float* oa     = ws + 4736000;
  float* sp     = ws + 4737024;
  float* op_    = ws + 4737088;
  int*   knn_i  = (int*)(ws + 4737152);  // 65536 ints
  // end: 4802688 floats

  prep_kernel<<<2181, 256, 0, stream>>>(aw1, aw2, lw3, pw2,
      ag1, ab1, abt1, pg1, pb1, pbt1,
      aw1pk, aw2pk, wppk, sa, oa, sp, op_);

  gemm_k<false, false, false><<<dim3(32,4,2), 256, 0, stream>>>(
      w_start, x, b_start, nullptr, xf, 256, NP, 128);

  knn_kernel<<<256, 1024, 0, stream>>>(pos, knn_i);

  gemm_k<false, true, false><<<dim3(32,4,2), 256, 0, stream>>>(
      w_key,   xf, b_key,   nullptr, keyT,   256, NP, 256);
  gemm_k<false, true, false><<<dim3(32,4,2), 256, 0, stream>>>(
      w_query, xf, b_query, nullptr, queryT, 256, NP, 256);
  gemm_k<false, true, false><<<dim3(32,4,2), 256, 0, stream>>>(
      w_value, xf, b_value, nullptr, valueT, 256, NP, 256);

  fused_attn<<<1024, 256, 0, stream>>>(keyT, queryT, valueT, knn_i,
      pos, map_idx, P_anchor, adist,
      lw1, lw2, pw1, sp, op_, pb2,
      aw1pk, sa, oa, aw2pk, wppk, ab2, aggT);

  gemm_k<true, false, true><<<dim3(32,2,2), 256, 0, stream>>>(
      w_end, aggT, b_end, x, (float*)d_out, 128, NP, 256);
}